// Round 5
// baseline (12.417 us; speedup 1.0000x reference)
//
#include <hip/hip_runtime.h>

#define NHB 0x7f7f7f7fu
#define HIB 0x80808080u

#if __has_builtin(__builtin_amdgcn_sad_u8)
__device__ __forceinline__ unsigned sad8(unsigned a, unsigned b, unsigned c) {
    return __builtin_amdgcn_sad_u8(a, b, c);
}
#else
__device__ __forceinline__ unsigned sad8(unsigned a, unsigned b, unsigned c) {
    unsigned d;
    asm("v_sad_u8 %0, %1, %2, %3" : "=v"(d) : "v"(a), "v"(b), "v"(c));
    return d;
}
#endif

__device__ __forceinline__ unsigned quantq(float v) {
    // (x * 256).clamp(0, 255) -> truncating int cast (nonneg after clamp)
    v = v * 256.0f;
    v = fminf(fmaxf(v, 0.0f), 255.0f);
    return (unsigned)v;
}

__device__ __forceinline__ unsigned pack4(float a, float b, float c, float d) {
    return quantq(a) | (quantq(b) << 8) | (quantq(c) << 16) | (quantq(d) << 24);
}

// exact per-byte (a+b)&255 for two a's sharing b's masked form; sad sums the bytes
__device__ __forceinline__ void swar2(unsigned a0, unsigned a1, unsigned b,
                                      unsigned& acc0, unsigned& acc1) {
    unsigned mb = b & NHB;
    unsigned s0 = ((a0 & NHB) + mb) ^ ((a0 ^ b) & HIB);
    unsigned s1 = ((a1 & NHB) + mb) ^ ((a1 ^ b) & HIB);
    acc0 = sad8(s0, 0u, acc0);
    acc1 = sad8(s1, 0u, acc1);
}

// 256 blocks (n,i) x 512 threads; each thread computes outputs (f, j) and (f+16, j),
// sharing one qX read stream. ~40 live VGPRs -> no spill (R2's failure was reg ARRAYS
// under a 128-VGPR launch_bounds cap; neither applies here).
__global__ __launch_bounds__(512) void adder2d_kernel(
    const float* __restrict__ x, const float* __restrict__ W,
    float* __restrict__ out)
{
    const int tid = threadIdx.x;
    const int bid = blockIdx.x;
    const int n = bid >> 5;   // batch
    const int i = bid & 31;   // output row

    __shared__ unsigned sQW[2304];      // 32 f-rows x 72 u32, byte-packed qW (288B rows)
    __shared__ unsigned sQX[32 * 96];   // 32 im2col byte rows, 384B stride, uint4-granule swizzled
    __shared__ unsigned sRowW[768];     // quantized input rows [c][kh][w] bytes

    // Phase 1a: quantize W -> bytes (u32 m covers W flat [4m..4m+3]; f-row = m/72)
    {
        const float4* W4 = (const float4*)W;
        for (int m = tid; m < 2304; m += 512) {
            float4 w = W4[m];
            sQW[m] = pack4(w.x, w.y, w.z, w.w);
        }
    }
    // Phase 1b: quantize input rows i-1..i+1 (out-of-range rows -> q=0)
    for (int m = tid; m < 768; m += 512) {
        int c = m / 24;
        int rr = m - c * 24;
        int kh = rr >> 3;
        int wq = (rr & 7) << 2;
        int row = i + kh - 1;
        unsigned pv = 0;
        if (row >= 0 && row < 32) {
            float4 v = *(const float4*)&x[((n * 32 + c) * 32 + row) * 32 + wq];
            pv = pack4(v.x, v.y, v.z, v.w);
        }
        sRowW[m] = pv;
    }
    __syncthreads();

    // Phase 2: build im2col byte rows sQX[j][k], k = c*9+kh*3+kw, uint4-granule swizzle g^(j&7)
    {
        const unsigned char* sRow = (const unsigned char*)sRowW;
        for (int m = tid; m < 2304; m += 512) {
            int j = m / 72;
            int p = m - j * 72;          // u32 index within logical row (0..71)
            unsigned v = 0;
#pragma unroll
            for (int e = 0; e < 4; ++e) {
                int k = 4 * p + e;
                int c = k / 9;
                int rem = k - 9 * c;
                int kh = rem / 3;
                int kw = rem - 3 * kh;
                int col = j + kw - 1;
                unsigned bv = (col >= 0 && col < 32) ? (unsigned)sRow[c * 96 + kh * 32 + col] : 0u;
                v |= bv << (8 * e);
            }
            int g = p >> 2, e2 = p & 3;
            sQX[j * 96 + (((g ^ (j & 7)) << 2) + e2)] = v;
        }
    }
    __syncthreads();

    // Phase 3: two outputs per thread (f0, f0+16) sharing the qX stream.
    // qW reads: 2 distinct addrs/wave (broadcast). qX reads: 32 distinct uint4 spread
    // over all 32 banks by the granule swizzle (4 addrs per 4-bank span = data-minimum cycles).
    const int f0 = tid >> 5;          // 0..15
    const int j  = tid & 31;
    const int js = j & 7;
    const uint4* qw0 = (const uint4*)&sQW[f0 * 72];
    const uint4* qw1 = (const uint4*)&sQW[(f0 + 16) * 72];
    const uint4* qxr = (const uint4*)&sQX[j * 96];
    unsigned acc0 = 0, acc1 = 0;   // max 288*255 = 73440 < 2^32
#pragma unroll
    for (int g = 0; g < 18; ++g) {
        uint4 a0 = qw0[g];
        uint4 a1 = qw1[g];
        uint4 b  = qxr[g ^ js];
        swar2(a0.x, a1.x, b.x, acc0, acc1);
        swar2(a0.y, a1.y, b.y, acc0, acc1);
        swar2(a0.z, a1.z, b.z, acc0, acc1);
        swar2(a0.w, a1.w, b.w, acc0, acc1);
    }

    out[((n * 32 + f0) * 32 + i) * 32 + j]        = -(float)acc0 * (1.0f / 256.0f);
    out[((n * 32 + f0 + 16) * 32 + i) * 32 + j]   = -(float)acc1 * (1.0f / 256.0f);
}

extern "C" void kernel_launch(void* const* d_in, const int* in_sizes, int n_in,
                              void* d_out, int out_size, void* d_ws, size_t ws_size,
                              hipStream_t stream) {
    const float* x = (const float*)d_in[0];   // [8,32,32,32]
    const float* W = (const float*)d_in[1];   // [32,32,3,3]
    float* out = (float*)d_out;               // [8,32,32,32]
    adder2d_kernel<<<256, 512, 0, stream>>>(x, W, out);
}